// Round 7
// baseline (389.788 us; speedup 1.0000x reference)
//
#include <hip/hip_runtime.h>
#include <math.h>

// Problem constants
#define BB    256
#define NMAX  512
#define HH    256   // H
#define CC    64    // C
#define HID   512
#define NEGV  -1000000000.0f
#define MT    64    // d-rows per mlp block (M=64: 64 FLOP per B-byte)
#define SA_LD 264   // A-tile leading dim: 256 + 8 pad (bf16 elems)
#define TILE  512   // ushorts per swizzled (16n x 32k) weight tile = 1KB
#define KSTR  (32 * TILE)  // ushorts per kb slab (32 n-tiles)

typedef __attribute__((ext_vector_type(8))) short short8;   // 8 bf16 = 4 VGPRs
typedef __attribute__((ext_vector_type(4))) float floatx4;  // MFMA C/D

__device__ inline ushort f2bf(float x) {
    unsigned u = __float_as_uint(x);
    u = (u + 0x7FFFu + ((u >> 16) & 1u)) >> 16;   // RNE
    return (ushort)u;
}

// ---------------------------------------------------------------------------
// Fused prep kernel, grid = 512 blocks x 256 threads:
//   blocks [0,128):   convert W1 k-rows [0,512) -> swizzled lane-order bf16
//   blocks [128,256): convert W2 -> swizzled lane-order bf16
//   blocks [256,512): per-batch base vector v_b (fp32 exact)
// ---------------------------------------------------------------------------
__global__ __launch_bounds__(256) void prep_kernel(
    const float* __restrict__ W1, const float* __restrict__ W2,
    ushort* __restrict__ Wt1s, ushort* __restrict__ Wt2s,
    const float* __restrict__ nodes_hv, const float* __restrict__ class_cond,
    const float* __restrict__ b1,
    const int* __restrict__ dirns, const int* __restrict__ node_counts,
    float* __restrict__ v_ws)
{
    const int blk = blockIdx.x;
    const int t = threadIdx.x;

    __shared__ float s_conv[32][68];
    __shared__ float s_src[HH];
    __shared__ float s_cc[CC];

    if (blk < 256) {
        const float* W = (blk < 128) ? W1 : W2;
        ushort* out    = (blk < 128) ? Wt1s : Wt2s;
        const int bb  = blk & 127;
        const int kb  = bb >> 3, ntg = bb & 7;

        {
            const int kl = t >> 3, nn = (t & 7) * 8;
            const float* src = W + (size_t)(kb * 32 + kl) * HID + ntg * 64 + nn;
            *(float4*)&s_conv[kl][nn]     = *(const float4*)src;
            *(float4*)&s_conv[kl][nn + 4] = *(const float4*)(src + 4);
        }
        __syncthreads();

        const int ntl = t >> 6, ls = t & 63;
        const int qs = ls >> 4, l15s = ls & 15;
        short8 o;
        #pragma unroll
        for (int j = 0; j < 8; ++j)
            o[j] = (short)f2bf(s_conv[qs * 8 + j][ntl * 16 + l15s]);
        const int nt = ntg * 4 + ntl;
        *(short8*)(out + ((size_t)(kb * 32 + nt)) * TILE + ls * 8) = o;
    } else {
        const int b = blk - 256;
        const int nc   = node_counts[b];
        const int dirn = dirns[b];
        const int src_idx = nc - 1;

        s_src[t] = nodes_hv[((size_t)b * NMAX + src_idx) * HH + t];
        if (t < CC) s_cc[t] = class_cond[b * CC + t];
        __syncthreads();

        const int srcoff = (dirn == 1) ? HH : 0;

        const int j = 2 * t;
        float acc0 = b1[j];
        float acc1 = b1[j + 1];

        #pragma unroll 4
        for (int r = 0; r < HH; ++r) {
            const float s = s_src[r];
            const float* wp = W1 + (size_t)(srcoff + r) * HID + j;
            acc0 += s * wp[0];
            acc1 += s * wp[1];
        }
        #pragma unroll 4
        for (int c = 0; c < CC; ++c) {
            const float s = s_cc[c];
            const float* wp = W1 + (size_t)(2 * HH + c) * HID + j;
            acc0 += s * wp[0];
            acc1 += s * wp[1];
        }
        v_ws[b * HID + j]     = acc0;
        v_ws[b * HID + j + 1] = acc1;
    }
}

// ---------------------------------------------------------------------------
// Kernel 2: MFMA MLP, M=64, with in-loop B-fragment software pipelining.
// grid = (NMAX/MT, B), block = 256 (4 waves). Wave wv owns n in [wv*128,+128):
// 4 m-blocks x 8 n-tiles of 16x16x32 bf16.
// K-loops process 2 K-steps per unrolled iteration with two named fragment
// buffers; loads for step ks+1 issue before the MFMA batch of step ks.
// NO loads cross a barrier (R3 lesson: cross-barrier preload is unstable).
// LDS union 64 KB: A-tile (33.8 KB) then h1 in MFMA-fragment-tiled layout
// (64 KB, conflict-free lane-contiguous reads), then s_red (1 KB).
// ---------------------------------------------------------------------------
__global__ __launch_bounds__(256, 2) void mlp2(
    const float* __restrict__ nodes_hv,
    const ushort* __restrict__ Wt1s, const ushort* __restrict__ Wt2s,
    const float* __restrict__ b2, const float* __restrict__ W3,
    const float* __restrict__ b3,
    const int* __restrict__ dirns, const int* __restrict__ node_counts,
    const float* __restrict__ v_ws, float* __restrict__ scores)
{
    const int b  = blockIdx.y;
    const int d0 = blockIdx.x * MT;
    const int t  = threadIdx.x;
    const int lane = t & 63, wv = t >> 6;
    const int l15 = lane & 15, q = lane >> 4;

    __shared__ ushort s_u[32768];   // 64 KB union

    const int nc = node_counts[b];

    // Block-uniform early exit: whole tile masked off
    if (d0 >= nc - 1) {
        if (t < MT) scores[b * NMAX + d0 + t] = NEGV;
        return;
    }

    // dirn==1: cand occupies x[0:256) -> W1 k-rows [0:256) -> kb0=0; else kb0=8
    const int kb0 = (dirns[b] == 1) ? 0 : 8;

    // ---- stage cand tile (MT x 256 fp32 -> bf16 LDS, leading dim SA_LD) ----
    {
        const float4* src4 = (const float4*)nodes_hv + ((size_t)b * NMAX + d0) * (HH / 4);
        #pragma unroll
        for (int i = 0; i < (MT * HH / 4) / 256; ++i) {   // 16 iters
            int idx = t + i * 256;
            int row = idx >> 6, c4 = idx & 63;
            float4 v = src4[idx];
            ushort4 p;
            p.x = f2bf(v.x); p.y = f2bf(v.y); p.z = f2bf(v.z); p.w = f2bf(v.w);
            *(ushort4*)&s_u[row * SA_LD + c4 * 4] = p;
        }
    }
    __syncthreads();

    floatx4 acc[4][8];
    #pragma unroll
    for (int mb = 0; mb < 4; ++mb)
        #pragma unroll
        for (int tn = 0; tn < 8; ++tn)
            acc[mb][tn] = (floatx4){0.f, 0.f, 0.f, 0.f};

    short8 bfA[8], bfB[8];

    // ---- layer 1: K = 256 (8 K-steps of 32), pipelined pairs ----
    {
        const ushort* wb1 = Wt1s + ((size_t)kb0 * 32 + wv * 8) * TILE + lane * 8;
        #pragma unroll
        for (int tn = 0; tn < 8; ++tn)
            bfA[tn] = *(const short8*)(wb1 + tn * TILE);

        #pragma unroll
        for (int kp = 0; kp < 4; ++kp) {
            const int ks0 = 2 * kp, ks1 = 2 * kp + 1;
            // prefetch ks1 before consuming ks0
            {
                const ushort* wp = wb1 + (size_t)ks1 * KSTR;
                #pragma unroll
                for (int tn = 0; tn < 8; ++tn)
                    bfB[tn] = *(const short8*)(wp + tn * TILE);
            }
            {
                short8 a[4];
                #pragma unroll
                for (int mb = 0; mb < 4; ++mb)
                    a[mb] = *(const short8*)&s_u[(mb * 16 + l15) * SA_LD + ks0 * 32 + q * 8];
                #pragma unroll
                for (int tn = 0; tn < 8; ++tn)
                    #pragma unroll
                    for (int mb = 0; mb < 4; ++mb)
                        acc[mb][tn] = __builtin_amdgcn_mfma_f32_16x16x32_bf16(a[mb], bfA[tn], acc[mb][tn], 0, 0, 0);
            }
            // prefetch ks1+1 (next pair's first step) before consuming ks1
            if (kp < 3) {
                const ushort* wp = wb1 + (size_t)(ks1 + 1) * KSTR;
                #pragma unroll
                for (int tn = 0; tn < 8; ++tn)
                    bfA[tn] = *(const short8*)(wp + tn * TILE);
            }
            {
                short8 a[4];
                #pragma unroll
                for (int mb = 0; mb < 4; ++mb)
                    a[mb] = *(const short8*)&s_u[(mb * 16 + l15) * SA_LD + ks1 * 32 + q * 8];
                #pragma unroll
                for (int tn = 0; tn < 8; ++tn)
                    #pragma unroll
                    for (int mb = 0; mb < 4; ++mb)
                        acc[mb][tn] = __builtin_amdgcn_mfma_f32_16x16x32_bf16(a[mb], bfB[tn], acc[mb][tn], 0, 0, 0);
            }
        }
    }
    __syncthreads();   // all waves done reading cand tile before h1 overwrites union

    const int n0 = wv * 128;

    // ---- epilogue 1: h1 = relu(acc + v_b) -> tiled LDS layout ----
    // n = n0 + tn*16 + l15 -> ks_w = wv*4 + (tn>>1); qr = (tn&1)*2 + (l15>>3); j = l15&7
    // row = mb*16 + q*4 + r -> L = qr*16 + (q*4+r)
    {
        const int j_w = l15 & 7;
        #pragma unroll
        for (int tn = 0; tn < 8; ++tn) {
            const int n = n0 + tn * 16 + l15;
            const float v = v_ws[b * HID + n];
            const int ks_w = wv * 4 + (tn >> 1);
            const int qr   = ((tn & 1) << 1) + (l15 >> 3);
            #pragma unroll
            for (int mb = 0; mb < 4; ++mb) {
                #pragma unroll
                for (int r = 0; r < 4; ++r) {
                    float h = acc[mb][tn][r] + v;          // C/D: row=q*4+r, col=l15
                    h = h > 0.f ? h : 0.f;
                    s_u[((mb * 16 + ks_w) * 64 + qr * 16 + q * 4 + r) * 8 + j_w] = f2bf(h);
                }
            }
        }
    }
    __syncthreads();

    // ---- layer 2: K = 512 (16 K-steps), pipelined pairs ----
    #pragma unroll
    for (int mb = 0; mb < 4; ++mb)
        #pragma unroll
        for (int tn = 0; tn < 8; ++tn)
            acc[mb][tn] = (floatx4){0.f, 0.f, 0.f, 0.f};
    {
        const ushort* wb2 = Wt2s + ((size_t)wv * 8) * TILE + lane * 8;
        #pragma unroll
        for (int tn = 0; tn < 8; ++tn)
            bfA[tn] = *(const short8*)(wb2 + tn * TILE);

        #pragma unroll
        for (int kp = 0; kp < 8; ++kp) {
            const int ks0 = 2 * kp, ks1 = 2 * kp + 1;
            {
                const ushort* wp = wb2 + (size_t)ks1 * KSTR;
                #pragma unroll
                for (int tn = 0; tn < 8; ++tn)
                    bfB[tn] = *(const short8*)(wp + tn * TILE);
            }
            {
                short8 a[4];
                #pragma unroll
                for (int mb = 0; mb < 4; ++mb)
                    a[mb] = *(const short8*)&s_u[((mb * 16 + ks0) * 64 + lane) * 8];
                #pragma unroll
                for (int tn = 0; tn < 8; ++tn)
                    #pragma unroll
                    for (int mb = 0; mb < 4; ++mb)
                        acc[mb][tn] = __builtin_amdgcn_mfma_f32_16x16x32_bf16(a[mb], bfA[tn], acc[mb][tn], 0, 0, 0);
            }
            if (kp < 7) {
                const ushort* wp = wb2 + (size_t)(ks1 + 1) * KSTR;
                #pragma unroll
                for (int tn = 0; tn < 8; ++tn)
                    bfA[tn] = *(const short8*)(wp + tn * TILE);
            }
            {
                short8 a[4];
                #pragma unroll
                for (int mb = 0; mb < 4; ++mb)
                    a[mb] = *(const short8*)&s_u[((mb * 16 + ks1) * 64 + lane) * 8];
                #pragma unroll
                for (int tn = 0; tn < 8; ++tn)
                    #pragma unroll
                    for (int mb = 0; mb < 4; ++mb)
                        acc[mb][tn] = __builtin_amdgcn_mfma_f32_16x16x32_bf16(a[mb], bfB[tn], acc[mb][tn], 0, 0, 0);
            }
        }
    }

    // ---- epilogue 2: p = relu(acc + b2) . W3, reduce over n ----
    float p[4][4] = {{0,0,0,0},{0,0,0,0},{0,0,0,0},{0,0,0,0}};
    #pragma unroll
    for (int tn = 0; tn < 8; ++tn) {
        const int n  = n0 + tn * 16 + l15;
        const float bb = b2[n];
        const float w3 = W3[n];
        #pragma unroll
        for (int mb = 0; mb < 4; ++mb)
            #pragma unroll
            for (int r = 0; r < 4; ++r) {
                float h = acc[mb][tn][r] + bb;
                h = h > 0.f ? h : 0.f;
                p[mb][r] += h * w3;
            }
    }
    __syncthreads();   // h1 region dead; safe to reuse union for s_red
    float* s_red = (float*)s_u;   // [4 waves][MT]
    #pragma unroll
    for (int mb = 0; mb < 4; ++mb)
        #pragma unroll
        for (int r = 0; r < 4; ++r) {
            float v = p[mb][r];
            v += __shfl_xor(v, 1, 64);
            v += __shfl_xor(v, 2, 64);
            v += __shfl_xor(v, 4, 64);
            v += __shfl_xor(v, 8, 64);
            if (l15 == 0) s_red[wv * MT + mb * 16 + q * 4 + r] = v;
        }
    __syncthreads();
    if (t < MT) {
        const float s = s_red[0 * MT + t] + s_red[1 * MT + t] +
                        s_red[2 * MT + t] + s_red[3 * MT + t] + b3[0];
        const int d = d0 + t;
        scores[b * NMAX + d] = (d < nc - 1) ? s : NEGV;
    }
}

// ---------------------------------------------------------------------------
// Kernel 3: per-batch masked log-softmax NLL. grid = B, block = 256.
// ---------------------------------------------------------------------------
__global__ __launch_bounds__(256) void loss_kernel(
    const float* __restrict__ scores, const int* __restrict__ dests,
    float* __restrict__ out)
{
    const int b = blockIdx.x;
    const int t = threadIdx.x;
    __shared__ float red[4];

    const float s0 = scores[b * NMAX + t];
    const float s1 = scores[b * NMAX + t + 256];

    const int lane = t & 63, wv = t >> 6;

    float mx = fmaxf(s0, s1);
    #pragma unroll
    for (int off = 32; off > 0; off >>= 1) mx = fmaxf(mx, __shfl_down(mx, off, 64));
    if (lane == 0) red[wv] = mx;
    __syncthreads();
    mx = fmaxf(fmaxf(red[0], red[1]), fmaxf(red[2], red[3]));
    __syncthreads();

    float e = __expf(s0 - mx) + __expf(s1 - mx);
    #pragma unroll
    for (int off = 32; off > 0; off >>= 1) e += __shfl_down(e, off, 64);
    if (lane == 0) red[wv] = e;
    __syncthreads();

    if (t == 0) {
        const float sum = red[0] + red[1] + red[2] + red[3];
        const float sd = scores[b * NMAX + dests[b]];
        out[b] = -(sd - mx - logf(sum));
    }
}

// ---------------------------------------------------------------------------
extern "C" void kernel_launch(void* const* d_in, const int* in_sizes, int n_in,
                              void* d_out, int out_size, void* d_ws, size_t ws_size,
                              hipStream_t stream) {
    const float* nodes_hv    = (const float*)d_in[0];
    const float* class_cond  = (const float*)d_in[1];
    const float* W1          = (const float*)d_in[2];
    const float* b1          = (const float*)d_in[3];
    const float* W2          = (const float*)d_in[4];
    const float* b2          = (const float*)d_in[5];
    const float* W3          = (const float*)d_in[6];
    const float* b3          = (const float*)d_in[7];
    const int*   dirns       = (const int*)d_in[8];
    const int*   node_counts = (const int*)d_in[9];
    const int*   dests       = (const int*)d_in[10];
    float* out = (float*)d_out;

    // ws layout (16B-aligned):
    //   Wt1s: 512 KiB | Wt2s: 512 KiB | v_ws: 512 KiB | scores: 512 KiB
    ushort* Wt1s   = (ushort*)d_ws;
    ushort* Wt2s   = Wt1s + 16 * KSTR;
    float*  v_ws   = (float*)(Wt2s + 16 * KSTR);
    float*  scores = v_ws + BB * HID;

    prep_kernel<<<512, 256, 0, stream>>>(W1, W2, Wt1s, Wt2s,
                                         nodes_hv, class_cond, b1,
                                         dirns, node_counts, v_ws);
    mlp2<<<dim3(NMAX / MT, BB), 256, 0, stream>>>(
        nodes_hv, Wt1s, Wt2s, b2, W3, b3, dirns, node_counts, v_ws, scores);
    loss_kernel<<<BB, 256, 0, stream>>>(scores, dests, out);
}

// Round 8
// 318.192 us; speedup vs baseline: 1.2250x; 1.2250x over previous
//
#include <hip/hip_runtime.h>
#include <math.h>

// Problem constants
#define BB    256
#define NMAX  512
#define HH    256   // H
#define CC    64    // C
#define HID   512
#define NEGV  -1000000000.0f
#define MT    64    // d-rows per mlp block
#define NW    8     // waves per block (512 threads)
#define SA_LD 264   // A-tile leading dim: 256 + 8 pad (bf16 elems)
#define TILE  512   // ushorts per swizzled (16n x 32k) weight tile = 1KB
#define KSTR  (32 * TILE)  // ushorts per kb slab (32 n-tiles)

typedef __attribute__((ext_vector_type(8))) short short8;   // 8 bf16 = 4 VGPRs
typedef __attribute__((ext_vector_type(4))) float floatx4;  // MFMA C/D

__device__ inline ushort f2bf(float x) {
    unsigned u = __float_as_uint(x);
    u = (u + 0x7FFFu + ((u >> 16) & 1u)) >> 16;   // RNE
    return (ushort)u;
}

// ---------------------------------------------------------------------------
// Fused prep kernel, grid = 512 blocks x 256 threads:
//   blocks [0,128):   convert W1 k-rows [0,512) -> swizzled lane-order bf16
//   blocks [128,256): convert W2 -> swizzled lane-order bf16
//   blocks [256,512): per-batch base vector v_b (fp32 exact)
// ---------------------------------------------------------------------------
__global__ __launch_bounds__(256) void prep_kernel(
    const float* __restrict__ W1, const float* __restrict__ W2,
    ushort* __restrict__ Wt1s, ushort* __restrict__ Wt2s,
    const float* __restrict__ nodes_hv, const float* __restrict__ class_cond,
    const float* __restrict__ b1,
    const int* __restrict__ dirns, const int* __restrict__ node_counts,
    float* __restrict__ v_ws)
{
    const int blk = blockIdx.x;
    const int t = threadIdx.x;

    __shared__ float s_conv[32][68];
    __shared__ float s_src[HH];
    __shared__ float s_cc[CC];

    if (blk < 256) {
        const float* W = (blk < 128) ? W1 : W2;
        ushort* out    = (blk < 128) ? Wt1s : Wt2s;
        const int bb  = blk & 127;
        const int kb  = bb >> 3, ntg = bb & 7;

        {
            const int kl = t >> 3, nn = (t & 7) * 8;
            const float* src = W + (size_t)(kb * 32 + kl) * HID + ntg * 64 + nn;
            *(float4*)&s_conv[kl][nn]     = *(const float4*)src;
            *(float4*)&s_conv[kl][nn + 4] = *(const float4*)(src + 4);
        }
        __syncthreads();

        const int ntl = t >> 6, ls = t & 63;
        const int qs = ls >> 4, l15s = ls & 15;
        short8 o;
        #pragma unroll
        for (int j = 0; j < 8; ++j)
            o[j] = (short)f2bf(s_conv[qs * 8 + j][ntl * 16 + l15s]);
        const int nt = ntg * 4 + ntl;
        *(short8*)(out + ((size_t)(kb * 32 + nt)) * TILE + ls * 8) = o;
    } else {
        const int b = blk - 256;
        const int nc   = node_counts[b];
        const int dirn = dirns[b];
        const int src_idx = nc - 1;

        s_src[t] = nodes_hv[((size_t)b * NMAX + src_idx) * HH + t];
        if (t < CC) s_cc[t] = class_cond[b * CC + t];
        __syncthreads();

        const int srcoff = (dirn == 1) ? HH : 0;

        const int j = 2 * t;
        float acc0 = b1[j];
        float acc1 = b1[j + 1];

        #pragma unroll 4
        for (int r = 0; r < HH; ++r) {
            const float s = s_src[r];
            const float* wp = W1 + (size_t)(srcoff + r) * HID + j;
            acc0 += s * wp[0];
            acc1 += s * wp[1];
        }
        #pragma unroll 4
        for (int c = 0; c < CC; ++c) {
            const float s = s_cc[c];
            const float* wp = W1 + (size_t)(2 * HH + c) * HID + j;
            acc0 += s * wp[0];
            acc1 += s * wp[1];
        }
        v_ws[b * HID + j]     = acc0;
        v_ws[b * HID + j + 1] = acc1;
    }
}

// ---------------------------------------------------------------------------
// Kernel 2: MFMA MLP, M=64, 512 threads (8 waves). grid = (NMAX/MT, B).
// Wave wv owns n-chunk [wv*64, +64): 4 m-blocks x 4 n-tiles of 16x16x32.
// 2 blocks/CU (64 KB LDS) -> 16 waves/CU: M=64's doubled B-reuse (vs R5)
// at double R6's wave-level parallelism. Plain loads; compiler owns waitcnts
// (R3/R7: manual pipelining is unstable or defeated).
// LDS union (64 KB): A-tile (33.8 KB) -> h1 fragment-tiled (64 KB) -> s_red (2 KB).
//   h1 layout: offset(mb,ks,L,j) = ((mb*16+ks)*64+L)*8+j holds
//   h1[row=mb*16+(L&15)][k=ks*32+(L>>4)*8+j] -> lane-contiguous conflict-free b128.
// ---------------------------------------------------------------------------
__global__ __launch_bounds__(512, 4) void mlp2(
    const float* __restrict__ nodes_hv,
    const ushort* __restrict__ Wt1s, const ushort* __restrict__ Wt2s,
    const float* __restrict__ b2, const float* __restrict__ W3,
    const float* __restrict__ b3,
    const int* __restrict__ dirns, const int* __restrict__ node_counts,
    const float* __restrict__ v_ws, float* __restrict__ scores)
{
    const int b  = blockIdx.y;
    const int d0 = blockIdx.x * MT;
    const int t  = threadIdx.x;
    const int lane = t & 63, wv = t >> 6;     // wv in [0,8)
    const int l15 = lane & 15, q = lane >> 4;

    __shared__ ushort s_u[32768];   // 64 KB union

    const int nc = node_counts[b];

    // Block-uniform early exit: whole tile masked off
    if (d0 >= nc - 1) {
        if (t < MT) scores[b * NMAX + d0 + t] = NEGV;
        return;
    }

    // dirn==1: cand occupies x[0:256) -> W1 k-rows [0:256) -> kb0=0; else kb0=8
    const int kb0 = (dirns[b] == 1) ? 0 : 8;

    // ---- stage cand tile (MT x 256 fp32 -> bf16 LDS, leading dim SA_LD) ----
    {
        const float4* src4 = (const float4*)nodes_hv + ((size_t)b * NMAX + d0) * (HH / 4);
        #pragma unroll
        for (int i = 0; i < (MT * HH / 4) / 512; ++i) {   // 8 iters
            int idx = t + i * 512;
            int row = idx >> 6, c4 = idx & 63;
            float4 v = src4[idx];
            ushort4 p;
            p.x = f2bf(v.x); p.y = f2bf(v.y); p.z = f2bf(v.z); p.w = f2bf(v.w);
            *(ushort4*)&s_u[row * SA_LD + c4 * 4] = p;
        }
    }
    __syncthreads();

    floatx4 acc[4][4];
    #pragma unroll
    for (int mb = 0; mb < 4; ++mb)
        #pragma unroll
        for (int tn = 0; tn < 4; ++tn)
            acc[mb][tn] = (floatx4){0.f, 0.f, 0.f, 0.f};

    // ---- layer 1: K = 256 (8 K-steps of 32) ----
    {
        const ushort* wb1 = Wt1s + ((size_t)kb0 * 32 + wv * 4) * TILE + lane * 8;
        #pragma unroll
        for (int ks = 0; ks < 8; ++ks) {
            const ushort* wp = wb1 + (size_t)ks * KSTR;
            short8 bfr[4];
            #pragma unroll
            for (int tn = 0; tn < 4; ++tn)
                bfr[tn] = *(const short8*)(wp + tn * TILE);
            short8 a[4];
            #pragma unroll
            for (int mb = 0; mb < 4; ++mb)
                a[mb] = *(const short8*)&s_u[(mb * 16 + l15) * SA_LD + ks * 32 + q * 8];
            #pragma unroll
            for (int tn = 0; tn < 4; ++tn)
                #pragma unroll
                for (int mb = 0; mb < 4; ++mb)
                    acc[mb][tn] = __builtin_amdgcn_mfma_f32_16x16x32_bf16(a[mb], bfr[tn], acc[mb][tn], 0, 0, 0);
        }
    }
    __syncthreads();   // all waves done reading cand tile before h1 overwrites union

    const int n0 = wv * 64;

    // ---- epilogue 1: h1 = relu(acc + v_b) -> fragment-tiled LDS ----
    // n = n0 + tn*16 + l15 -> ks_w = wv*2 + (tn>>1); qr = ((tn&1)<<1)+(l15>>3); j_w = l15&7
    {
        const int j_w = l15 & 7;
        #pragma unroll
        for (int tn = 0; tn < 4; ++tn) {
            const int n = n0 + tn * 16 + l15;
            const float v = v_ws[b * HID + n];
            const int ks_w = wv * 2 + (tn >> 1);
            const int qr   = ((tn & 1) << 1) + (l15 >> 3);
            #pragma unroll
            for (int mb = 0; mb < 4; ++mb) {
                #pragma unroll
                for (int r = 0; r < 4; ++r) {
                    float h = acc[mb][tn][r] + v;          // C/D: row=q*4+r, col=l15
                    h = h > 0.f ? h : 0.f;
                    s_u[((mb * 16 + ks_w) * 64 + qr * 16 + q * 4 + r) * 8 + j_w] = f2bf(h);
                }
            }
        }
    }
    __syncthreads();

    // ---- layer 2: K = 512 (16 K-steps) ----
    #pragma unroll
    for (int mb = 0; mb < 4; ++mb)
        #pragma unroll
        for (int tn = 0; tn < 4; ++tn)
            acc[mb][tn] = (floatx4){0.f, 0.f, 0.f, 0.f};
    {
        const ushort* wb2 = Wt2s + ((size_t)wv * 4) * TILE + lane * 8;
        #pragma unroll
        for (int ks = 0; ks < 16; ++ks) {
            const ushort* wp = wb2 + (size_t)ks * KSTR;
            short8 bfr[4];
            #pragma unroll
            for (int tn = 0; tn < 4; ++tn)
                bfr[tn] = *(const short8*)(wp + tn * TILE);
            short8 a[4];
            #pragma unroll
            for (int mb = 0; mb < 4; ++mb)
                a[mb] = *(const short8*)&s_u[((mb * 16 + ks) * 64 + lane) * 8];
            #pragma unroll
            for (int tn = 0; tn < 4; ++tn)
                #pragma unroll
                for (int mb = 0; mb < 4; ++mb)
                    acc[mb][tn] = __builtin_amdgcn_mfma_f32_16x16x32_bf16(a[mb], bfr[tn], acc[mb][tn], 0, 0, 0);
        }
    }

    // ---- epilogue 2: p = relu(acc + b2) . W3, reduce over n ----
    float p[4][4] = {{0,0,0,0},{0,0,0,0},{0,0,0,0},{0,0,0,0}};
    #pragma unroll
    for (int tn = 0; tn < 4; ++tn) {
        const int n  = n0 + tn * 16 + l15;
        const float bb = b2[n];
        const float w3 = W3[n];
        #pragma unroll
        for (int mb = 0; mb < 4; ++mb)
            #pragma unroll
            for (int r = 0; r < 4; ++r) {
                float h = acc[mb][tn][r] + bb;
                h = h > 0.f ? h : 0.f;
                p[mb][r] += h * w3;
            }
    }
    __syncthreads();   // h1 region dead; safe to reuse union for s_red
    float* s_red = (float*)s_u;   // [8 waves][MT]
    #pragma unroll
    for (int mb = 0; mb < 4; ++mb)
        #pragma unroll
        for (int r = 0; r < 4; ++r) {
            float v = p[mb][r];
            v += __shfl_xor(v, 1, 64);
            v += __shfl_xor(v, 2, 64);
            v += __shfl_xor(v, 4, 64);
            v += __shfl_xor(v, 8, 64);
            if (l15 == 0) s_red[wv * MT + mb * 16 + q * 4 + r] = v;
        }
    __syncthreads();
    if (t < MT) {
        float s = b3[0];
        #pragma unroll
        for (int w = 0; w < NW; ++w) s += s_red[w * MT + t];
        const int d = d0 + t;
        scores[b * NMAX + d] = (d < nc - 1) ? s : NEGV;
    }
}

// ---------------------------------------------------------------------------
// Kernel 3: per-batch masked log-softmax NLL. grid = B, block = 256.
// ---------------------------------------------------------------------------
__global__ __launch_bounds__(256) void loss_kernel(
    const float* __restrict__ scores, const int* __restrict__ dests,
    float* __restrict__ out)
{
    const int b = blockIdx.x;
    const int t = threadIdx.x;
    __shared__ float red[4];

    const float s0 = scores[b * NMAX + t];
    const float s1 = scores[b * NMAX + t + 256];

    const int lane = t & 63, wv = t >> 6;

    float mx = fmaxf(s0, s1);
    #pragma unroll
    for (int off = 32; off > 0; off >>= 1) mx = fmaxf(mx, __shfl_down(mx, off, 64));
    if (lane == 0) red[wv] = mx;
    __syncthreads();
    mx = fmaxf(fmaxf(red[0], red[1]), fmaxf(red[2], red[3]));
    __syncthreads();

    float e = __expf(s0 - mx) + __expf(s1 - mx);
    #pragma unroll
    for (int off = 32; off > 0; off >>= 1) e += __shfl_down(e, off, 64);
    if (lane == 0) red[wv] = e;
    __syncthreads();

    if (t == 0) {
        const float sum = red[0] + red[1] + red[2] + red[3];
        const float sd = scores[b * NMAX + dests[b]];
        out[b] = -(sd - mx - logf(sum));
    }
}

// ---------------------------------------------------------------------------
extern "C" void kernel_launch(void* const* d_in, const int* in_sizes, int n_in,
                              void* d_out, int out_size, void* d_ws, size_t ws_size,
                              hipStream_t stream) {
    const float* nodes_hv    = (const float*)d_in[0];
    const float* class_cond  = (const float*)d_in[1];
    const float* W1          = (const float*)d_in[2];
    const float* b1          = (const float*)d_in[3];
    const float* W2          = (const float*)d_in[4];
    const float* b2          = (const float*)d_in[5];
    const float* W3          = (const float*)d_in[6];
    const float* b3          = (const float*)d_in[7];
    const int*   dirns       = (const int*)d_in[8];
    const int*   node_counts = (const int*)d_in[9];
    const int*   dests       = (const int*)d_in[10];
    float* out = (float*)d_out;

    // ws layout (16B-aligned):
    //   Wt1s: 512 KiB | Wt2s: 512 KiB | v_ws: 512 KiB | scores: 512 KiB
    ushort* Wt1s   = (ushort*)d_ws;
    ushort* Wt2s   = Wt1s + 16 * KSTR;
    float*  v_ws   = (float*)(Wt2s + 16 * KSTR);
    float*  scores = v_ws + BB * HID;

    prep_kernel<<<512, 256, 0, stream>>>(W1, W2, Wt1s, Wt2s,
                                         nodes_hv, class_cond, b1,
                                         dirns, node_counts, v_ws);
    mlp2<<<dim3(NMAX / MT, BB), 512, 0, stream>>>(
        nodes_hv, Wt1s, Wt2s, b2, W3, b3, dirns, node_counts, v_ws, scores);
    loss_kernel<<<BB, 256, 0, stream>>>(scores, dests, out);
}